// Round 7
// baseline (398.497 us; speedup 1.0000x reference)
//
#include <hip/hip_runtime.h>
#include <hip/hip_bf16.h>

#define H 8
#define DM 512
#define DK 64
#define LSEQ 4096
#define NB 2
#define NSPLIT 2
#define KSPAN (LSEQ / NSPLIT)   // keys per split = 2048
#define NIT (KSPAN / 64)        // 32 k-tiles per block

// 0.125 (1/sqrt(DK)) * log2(e): folded into Q so softmax uses exp2 directly
#define QSCALE 0.18033688011112042f

typedef float f32x4 __attribute__((ext_vector_type(4)));
typedef __bf16 bf16x8 __attribute__((ext_vector_type(8)));
typedef __bf16 bf16x2 __attribute__((ext_vector_type(2)));
typedef unsigned short u16;

__device__ __forceinline__ u16 f2bf(float f) {
    union { float f; unsigned u; } v{f};
    return (u16)((v.u + 0x8000u) >> 16);
}

__device__ __forceinline__ unsigned pkbf(float a, float b) {
#if __has_builtin(__builtin_amdgcn_cvt_pk_bf16_f32)
    union { bf16x2 v; unsigned u; } x;
    x.v = __builtin_amdgcn_cvt_pk_bf16_f32(a, b);
    return x.u;
#else
    union { float f; unsigned u; } x{a}, y{b};
    return ((x.u + 0x8000u) >> 16) | ((y.u + 0x8000u) & 0xffff0000u);
#endif
}

__device__ __forceinline__ ushort4 cvt4(float4 a) {
    union { ushort4 s; uint2 u; } o;
    o.u.x = pkbf(a.x, a.y);
    o.u.y = pkbf(a.z, a.w);
    return o.s;
}

__device__ __forceinline__ float2 ubf2(unsigned u) {
    union { float f; unsigned v; } a, b;
    a.v = u << 16;
    b.v = u & 0xffff0000u;
    return make_float2(a.f, b.f);
}

__device__ __forceinline__ float fexp2(float x) {
#if __has_builtin(__builtin_amdgcn_exp2f)
    return __builtin_amdgcn_exp2f(x);
#else
    return exp2f(x);
#endif
}

__device__ __forceinline__ f32x4 mfma32(bf16x8 a, bf16x8 b, f32x4 c) {
    return __builtin_amdgcn_mfma_f32_16x16x32_bf16(a, b, c, 0, 0, 0);
}

// ---------------------------------------------------------------------------
// QKV projection, 128x128 tile, fp32 staging + inline cvt (r4 structure —
// the r6 bf16 prepass cost more than it saved; proj is not load-bound).
// mode 0 (Q): scaled by QSCALE, (b,h,s,d); 1 (K): (b,h,s,d); 2 (V): (b,h,d,s)
// via LDS transpose.
// ---------------------------------------------------------------------------
__launch_bounds__(256, 2)
__global__ void proj_qkv(const float* __restrict__ Xq, const float* __restrict__ Xk,
                         const float* __restrict__ Xv,
                         const float* __restrict__ Wq, const float* __restrict__ Wk,
                         const float* __restrict__ Wv,
                         const float* __restrict__ bq, const float* __restrict__ bk,
                         const float* __restrict__ bv,
                         u16* __restrict__ qo, u16* __restrict__ ko, u16* __restrict__ vo)
{
    const int mode = blockIdx.z;
    const float* X    = (mode == 0) ? Xq : (mode == 1) ? Xk : Xv;
    const float* W    = (mode == 0) ? Wq : (mode == 1) ? Wk : Wv;
    const float* bias = (mode == 0) ? bq : (mode == 1) ? bk : bv;
    u16* out          = (mode == 0) ? qo : (mode == 1) ? ko : vo;

    __shared__ __align__(16) u16 smem[2][128][72];
    auto As = smem[0];
    auto Bs = smem[1];

    const int tid  = threadIdx.x;
    const int wave = tid >> 6;
    const int lane = tid & 63;
    const int g    = lane >> 4;
    const int ln   = lane & 15;
    const int wr   = wave >> 1;
    const int wc   = wave & 1;

    const int m0 = blockIdx.x * 128;
    const int n0 = blockIdx.y * 128;

    f32x4 acc[4][4] = {};

    for (int kb = 0; kb < DM; kb += 64) {
        #pragma unroll
        for (int i = 0; i < 8; ++i) {
            int idx = tid + 256 * i;
            int row = idx >> 4;
            int col = (idx & 15) * 4;
            float4 a = *(const float4*)(X + (size_t)(m0 + row) * DM + kb + col);
            *(ushort4*)&As[row][col] = cvt4(a);
            float4 w = *(const float4*)(W + (size_t)(n0 + row) * DM + kb + col);
            *(ushort4*)&Bs[row][col] = cvt4(w);
        }
        __syncthreads();

        bf16x8 af[4][2], bf[4][2];
        #pragma unroll
        for (int t = 0; t < 4; ++t) {
            af[t][0] = *(const bf16x8*)&As[wr * 64 + t * 16 + ln][g * 8];
            af[t][1] = *(const bf16x8*)&As[wr * 64 + t * 16 + ln][32 + g * 8];
            bf[t][0] = *(const bf16x8*)&Bs[wc * 64 + t * 16 + ln][g * 8];
            bf[t][1] = *(const bf16x8*)&Bs[wc * 64 + t * 16 + ln][32 + g * 8];
        }
        #pragma unroll
        for (int mt = 0; mt < 4; ++mt)
            #pragma unroll
            for (int nt = 0; nt < 4; ++nt) {
                acc[mt][nt] = mfma32(af[mt][0], bf[nt][0], acc[mt][nt]);
                acc[mt][nt] = mfma32(af[mt][1], bf[nt][1], acc[mt][nt]);
            }
        __syncthreads();
    }

    if (mode != 2) {
        #pragma unroll
        for (int nt = 0; nt < 4; ++nt) {
            int n  = n0 + wc * 64 + nt * 16 + ln;
            float bias_n = bias[n];
            int hh = n >> 6;
            int d  = n & (DK - 1);
            #pragma unroll
            for (int mt = 0; mt < 4; ++mt)
                #pragma unroll
                for (int r = 0; r < 4; ++r) {
                    int m  = m0 + wr * 64 + mt * 16 + g * 4 + r;
                    int bb = m >> 12;
                    int s  = m & (LSEQ - 1);
                    float val = acc[mt][nt][r] + bias_n;
                    if (mode == 0) val *= QSCALE;
                    out[(size_t)((bb * H + hh) * LSEQ + s) * DK + d] = f2bf(val);
                }
        }
    } else {
        u16* Ts = &smem[0][0][0];
        #pragma unroll
        for (int nt = 0; nt < 4; ++nt) {
            int dl = wc * 64 + nt * 16 + ln;
            float bias_n = bias[n0 + dl];
            #pragma unroll
            for (int mt = 0; mt < 4; ++mt)
                #pragma unroll
                for (int r = 0; r < 4; ++r) {
                    int sl = wr * 64 + mt * 16 + g * 4 + r;
                    Ts[dl * 136 + sl] = f2bf(acc[mt][nt][r] + bias_n);
                }
        }
        __syncthreads();
        int dl   = tid >> 1;
        int half = tid & 1;
        int n  = n0 + dl;
        int hh = n >> 6;
        int d  = n & (DK - 1);
        int bb = m0 >> 12;
        int s0 = (m0 & (LSEQ - 1)) + half * 64;
        u16* dst = out + ((size_t)((bb * H + hh) * DK + d) * LSEQ + s0);
        const u16* srcp = Ts + dl * 136 + half * 64;
        #pragma unroll
        for (int i = 0; i < 8; ++i)
            *(uint4*)(dst + i * 8) = *(const uint4*)(srcp + i * 8);
    }
}

// ---------------------------------------------------------------------------
// Flash attention, transposed-S, q=32/wave, 2-way split-K.
// Round-7: per-block 32-bit tile bitmask (one __ballot per 64-key tile,
// computed once in the prologue, held in ONE uniform register). Fast path
// per iter: wave-uniform branch, zero mask loads, zero cndmasks. Unlike the
// r5 attempt, nothing vector-valued lives across the score window -> no
// spill (tripwire: WRITE_SIZE must stay ~16.9 MB).
// ---------------------------------------------------------------------------
__launch_bounds__(256, 4)
__global__ void flash(const u16* __restrict__ qws, const u16* __restrict__ kws,
                      const u16* __restrict__ vws, const int* __restrict__ mask,
                      u16* __restrict__ Opart, float* __restrict__ lpart)
{
    __shared__ u16 Ks[2][64][72];
    __shared__ u16 Vs[2][64][72];   // [d][pi(key)]

    const int tid   = threadIdx.x;
    const int wave  = tid >> 6;
    const int lane  = tid & 63;
    const int g     = lane >> 4;
    const int ln    = lane & 15;
    const int b     = blockIdx.z;
    const int h     = blockIdx.y;
    const int qblk  = blockIdx.x & 31;
    const int split = blockIdx.x >> 5;
    const int q0    = qblk * 128;
    const int kstart = split * KSPAN;

    const u16* qp = qws + ((size_t)((b * H + h) * LSEQ) + q0 + wave * 32 + ln) * DK;
    const u16* kp = kws + (size_t)(b * H + h) * LSEQ * DK;
    const u16* vp = vws + (size_t)(b * H + h) * DK * LSEQ;
    const int* mp = mask + b * LSEQ;

    // tile bitmask: bit t set iff all 64 keys of tile t are unmasked
    unsigned tilemask = 0;
    for (int t = 0; t < NIT; ++t) {
        int mval = mp[kstart + t * 64 + lane];
        unsigned long long bal = __ballot(mval != 0);
        if (bal == 0xFFFFFFFFFFFFFFFFull) tilemask |= (1u << t);
    }

    bf16x8 qf[2][2];
    qf[0][0] = *(const bf16x8*)(qp + g * 8);
    qf[0][1] = *(const bf16x8*)(qp + 32 + g * 8);
    qf[1][0] = *(const bf16x8*)(qp + 16 * DK + g * 8);
    qf[1][1] = *(const bf16x8*)(qp + 16 * DK + 32 + g * 8);

    union OU { unsigned u[4]; bf16x8 v; } onesu;
    onesu.u[0] = onesu.u[1] = onesu.u[2] = onesu.u[3] = 0x3F803F80u;
    const bf16x8 vones = onesu.v;

    f32x4 accO[2][4] = {};
    f32x4 accL[2] = {};

    const int row = tid >> 3;
    const int c   = tid & 7;
    const int vcol0 = ((2 * c) & 3) * 16 + (c >> 1) * 4;

    uint4 kr0, kr1, vr0, vr1;
    kr0 = *(const uint4*)(kp + (size_t)(kstart + row) * DK + c * 8);
    kr1 = *(const uint4*)(kp + (size_t)(kstart + row + 32) * DK + c * 8);
    vr0 = *(const uint4*)(vp + (size_t)row * LSEQ + kstart + c * 8);
    vr1 = *(const uint4*)(vp + (size_t)(row + 32) * LSEQ + kstart + c * 8);
    *(uint4*)&Ks[0][row][c * 8]      = kr0;
    *(uint4*)&Ks[0][row + 32][c * 8] = kr1;
    *(uint2*)&Vs[0][row][vcol0]           = make_uint2(vr0.x, vr0.y);
    *(uint2*)&Vs[0][row][vcol0 + 16]      = make_uint2(vr0.z, vr0.w);
    *(uint2*)&Vs[0][row + 32][vcol0]      = make_uint2(vr1.x, vr1.y);
    *(uint2*)&Vs[0][row + 32][vcol0 + 16] = make_uint2(vr1.z, vr1.w);

    for (int it = 0; it < NIT; ++it) {
        const int cur = it & 1;
        const int k0  = kstart + it * 64;
        __syncthreads();

        if (it < NIT - 1) {
            int kn = k0 + 64;
            kr0 = *(const uint4*)(kp + (size_t)(kn + row) * DK + c * 8);
            kr1 = *(const uint4*)(kp + (size_t)(kn + row + 32) * DK + c * 8);
            vr0 = *(const uint4*)(vp + (size_t)row * LSEQ + kn + c * 8);
            vr1 = *(const uint4*)(vp + (size_t)(row + 32) * LSEQ + kn + c * 8);
        }

        // S^T = K . Q^T for both q-subtiles (K-frags read once)
        f32x4 sc[2][4];
        #pragma unroll
        for (int kb = 0; kb < 4; ++kb) {
            bf16x8 kf0 = *(const bf16x8*)&Ks[cur][kb * 16 + ln][g * 8];
            bf16x8 kf1 = *(const bf16x8*)&Ks[cur][kb * 16 + ln][32 + g * 8];
            #pragma unroll
            for (int j = 0; j < 2; ++j) {
                f32x4 z = {};
                z = mfma32(kf0, qf[j][0], z);
                z = mfma32(kf1, qf[j][1], z);
                sc[j][kb] = z;
            }
        }

        // softmax numerators: wave-uniform fast path when tile fully unmasked
        if (tilemask & (1u << it)) {
            #pragma unroll
            for (int kb = 0; kb < 4; ++kb)
                #pragma unroll
                for (int j = 0; j < 2; ++j) {
                    sc[j][kb][0] = fexp2(sc[j][kb][0]);
                    sc[j][kb][1] = fexp2(sc[j][kb][1]);
                    sc[j][kb][2] = fexp2(sc[j][kb][2]);
                    sc[j][kb][3] = fexp2(sc[j][kb][3]);
                }
        } else {
            #pragma unroll
            for (int kb = 0; kb < 4; ++kb) {
                int4 mv = *(const int4*)(mp + k0 + kb * 16 + g * 4);
                #pragma unroll
                for (int j = 0; j < 2; ++j) {
                    sc[j][kb][0] = fexp2(mv.x ? sc[j][kb][0] : -1e9f);
                    sc[j][kb][1] = fexp2(mv.y ? sc[j][kb][1] : -1e9f);
                    sc[j][kb][2] = fexp2(mv.z ? sc[j][kb][2] : -1e9f);
                    sc[j][kb][3] = fexp2(mv.w ? sc[j][kb][3] : -1e9f);
                }
            }
        }

        // pack P fragments (score regs are A-layout under formal-k remap)
        union PU { unsigned u[4]; bf16x8 v; } p01[2], p23[2];
        #pragma unroll
        for (int j = 0; j < 2; ++j) {
            p01[j].u[0] = pkbf(sc[j][0][0], sc[j][0][1]);
            p01[j].u[1] = pkbf(sc[j][0][2], sc[j][0][3]);
            p01[j].u[2] = pkbf(sc[j][1][0], sc[j][1][1]);
            p01[j].u[3] = pkbf(sc[j][1][2], sc[j][1][3]);
            p23[j].u[0] = pkbf(sc[j][2][0], sc[j][2][1]);
            p23[j].u[1] = pkbf(sc[j][2][2], sc[j][2][3]);
            p23[j].u[2] = pkbf(sc[j][3][0], sc[j][3][1]);
            p23[j].u[3] = pkbf(sc[j][3][2], sc[j][3][3]);
        }

        // l row-sums via ones-MFMA; O += P . V
        #pragma unroll
        for (int j = 0; j < 2; ++j) {
            accL[j] = mfma32(p01[j].v, vones, accL[j]);
            accL[j] = mfma32(p23[j].v, vones, accL[j]);
        }
        #pragma unroll
        for (int t = 0; t < 4; ++t) {
            bf16x8 vb01 = *(const bf16x8*)&Vs[cur][t * 16 + ln][g * 16];
            bf16x8 vb23 = *(const bf16x8*)&Vs[cur][t * 16 + ln][g * 16 + 8];
            #pragma unroll
            for (int j = 0; j < 2; ++j) {
                accO[j][t] = mfma32(p01[j].v, vb01, accO[j][t]);
                accO[j][t] = mfma32(p23[j].v, vb23, accO[j][t]);
            }
        }

        if (it < NIT - 1) {
            int nxt = 1 - cur;
            *(uint4*)&Ks[nxt][row][c * 8]      = kr0;
            *(uint4*)&Ks[nxt][row + 32][c * 8] = kr1;
            *(uint2*)&Vs[nxt][row][vcol0]           = make_uint2(vr0.x, vr0.y);
            *(uint2*)&Vs[nxt][row][vcol0 + 16]      = make_uint2(vr0.z, vr0.w);
            *(uint2*)&Vs[nxt][row + 32][vcol0]      = make_uint2(vr1.x, vr1.y);
            *(uint2*)&Vs[nxt][row + 32][vcol0 + 16] = make_uint2(vr1.z, vr1.w);
        }
    }

    // accL[j][r] = l for q-row (g*4+r), replicated over ln.
    const size_t PLANE = (size_t)NB * LSEQ * DM;
    u16* opp = Opart + (size_t)split * PLANE;

    #pragma unroll
    for (int j = 0; j < 2; ++j) {
        if (ln == 0) {
            #pragma unroll
            for (int r = 0; r < 4; ++r)
                lpart[(size_t)split * (NB * H * LSEQ) + ((size_t)(b * H + h) * LSEQ)
                      + q0 + wave * 32 + j * 16 + g * 4 + r] = accL[j][r];
        }
        #pragma unroll
        for (int r = 0; r < 4; ++r) {
            float linv = 1.0f / accL[j][r];
            size_t base = ((size_t)(b * LSEQ) + q0 + wave * 32 + j * 16 + g * 4 + r) * DM + h * DK;
            #pragma unroll
            for (int t = 0; t < 4; ++t)
                opp[base + t * 16 + ln] = f2bf(accO[j][t][r] * linv);
        }
    }
}

// ---------------------------------------------------------------------------
// Split-K combine: ows = (l0*Ohat0 + l1*Ohat1) / (l0+l1), bf16 out.
// (Separate kernel — r5's fusion into proj_out replicated the combine per
// n-tile and read both planes 8x: a measured regression.)
// ---------------------------------------------------------------------------
__launch_bounds__(256, 4)
__global__ void reduce_split(const u16* __restrict__ Opart, const float* __restrict__ lpart,
                             u16* __restrict__ ows)
{
    const size_t PLANE = (size_t)NB * LSEQ * DM;
    size_t gid  = (size_t)blockIdx.x * 256 + threadIdx.x;
    size_t flat = gid * 8;

    int b   = (int)(flat >> 21);            // LSEQ*DM = 2^21
    int rem = (int)(flat & ((1 << 21) - 1));
    int q   = rem >> 9;                      // DM = 512
    int hh  = (rem & 511) >> 6;
    size_t lidx = ((size_t)(b * H + hh) * LSEQ) + q;

    float l0 = lpart[lidx];
    float l1 = lpart[(size_t)NB * H * LSEQ + lidx];
    float inv = 1.0f / (l0 + l1);
    float w0 = l0 * inv, w1 = l1 * inv;

    uint4 c0 = *(const uint4*)(Opart + flat);
    uint4 c1 = *(const uint4*)(Opart + PLANE + flat);

    float o[8];
    {
        float2 a, bv;
        a = ubf2(c0.x); bv = ubf2(c1.x); o[0] = w0 * a.x + w1 * bv.x; o[1] = w0 * a.y + w1 * bv.y;
        a = ubf2(c0.y); bv = ubf2(c1.y); o[2] = w0 * a.x + w1 * bv.x; o[3] = w0 * a.y + w1 * bv.y;
        a = ubf2(c0.z); bv = ubf2(c1.z); o[4] = w0 * a.x + w1 * bv.x; o[5] = w0 * a.y + w1 * bv.y;
        a = ubf2(c0.w); bv = ubf2(c1.w); o[6] = w0 * a.x + w1 * bv.x; o[7] = w0 * a.y + w1 * bv.y;
    }
    uint4 r;
    r.x = pkbf(o[0], o[1]);
    r.y = pkbf(o[2], o[3]);
    r.z = pkbf(o[4], o[5]);
    r.w = pkbf(o[6], o[7]);
    *(uint4*)(ows + flat) = r;
}

// ---------------------------------------------------------------------------
// Output projection, 128x128 tile (wr/wc wave split — halves ows re-reads vs
// the 128x64 version): out = O @ Wo^T + bo, bf16 A, fp32 out.
// ---------------------------------------------------------------------------
__launch_bounds__(256, 2)
__global__ void proj_out(const u16* __restrict__ A, const float* __restrict__ Wo,
                         const float* __restrict__ bo, float* __restrict__ out)
{
    __shared__ u16 As[128][72];
    __shared__ u16 Bs[128][72];

    const int tid  = threadIdx.x;
    const int wave = tid >> 6;
    const int lane = tid & 63;
    const int g    = lane >> 4;
    const int ln   = lane & 15;
    const int wr   = wave >> 1;
    const int wc   = wave & 1;

    const int m0 = blockIdx.x * 128;
    const int n0 = blockIdx.y * 128;

    f32x4 acc[4][4] = {};

    for (int kb = 0; kb < DM; kb += 64) {
        #pragma unroll
        for (int i = 0; i < 4; ++i) {
            int idx = tid + 256 * i;           // 1024 uint4 chunks (A, bf16)
            int row = idx >> 3;
            int col = (idx & 7) * 8;
            *(uint4*)&As[row][col] = *(const uint4*)(A + (size_t)(m0 + row) * DM + kb + col);
        }
        #pragma unroll
        for (int i = 0; i < 8; ++i) {
            int idx = tid + 256 * i;           // 2048 float4 chunks (B, fp32->bf16)
            int row = idx >> 4;
            int col = (idx & 15) * 4;
            float4 w = *(const float4*)(Wo + (size_t)(n0 + row) * DM + kb + col);
            *(ushort4*)&Bs[row][col] = cvt4(w);
        }
        __syncthreads();

        bf16x8 af[4][2], bf[4][2];
        #pragma unroll
        for (int t = 0; t < 4; ++t) {
            af[t][0] = *(const bf16x8*)&As[wr * 64 + t * 16 + ln][g * 8];
            af[t][1] = *(const bf16x8*)&As[wr * 64 + t * 16 + ln][32 + g * 8];
            bf[t][0] = *(const bf16x8*)&Bs[wc * 64 + t * 16 + ln][g * 8];
            bf[t][1] = *(const bf16x8*)&Bs[wc * 64 + t * 16 + ln][32 + g * 8];
        }
        #pragma unroll
        for (int mt = 0; mt < 4; ++mt)
            #pragma unroll
            for (int nt = 0; nt < 4; ++nt) {
                acc[mt][nt] = mfma32(af[mt][0], bf[nt][0], acc[mt][nt]);
                acc[mt][nt] = mfma32(af[mt][1], bf[nt][1], acc[mt][nt]);
            }
        __syncthreads();
    }

    #pragma unroll
    for (int nt = 0; nt < 4; ++nt) {
        int n = n0 + wc * 64 + nt * 16 + ln;
        float bias_n = bo[n];
        #pragma unroll
        for (int mt = 0; mt < 4; ++mt)
            #pragma unroll
            for (int r = 0; r < 4; ++r) {
                int m = m0 + wr * 64 + mt * 16 + g * 4 + r;
                out[(size_t)m * DM + n] = acc[mt][nt][r] + bias_n;
            }
    }
}

// ---------------------------------------------------------------------------
extern "C" void kernel_launch(void* const* d_in, const int* in_sizes, int n_in,
                              void* d_out, int out_size, void* d_ws, size_t ws_size,
                              hipStream_t stream) {
    (void)in_sizes; (void)n_in; (void)out_size; (void)ws_size;

    const float* query = (const float*)d_in[0];
    const float* key   = (const float*)d_in[1];
    const float* value = (const float*)d_in[2];
    const int*   mask  = (const int*)d_in[3];
    const float* Wq = (const float*)d_in[4];
    const float* bq = (const float*)d_in[5];
    const float* Wk = (const float*)d_in[6];
    const float* bk = (const float*)d_in[7];
    const float* Wv = (const float*)d_in[8];
    const float* bv = (const float*)d_in[9];
    const float* Wo = (const float*)d_in[10];
    const float* bo = (const float*)d_in[11];
    float* out = (float*)d_out;

    // ws layout (u16 elems): qws | kws | vws | ows | Opart(2 planes) | lpart(f32)
    const size_t PLANE = (size_t)NB * H * LSEQ * DK;   // 4,194,304
    u16* qws   = (u16*)d_ws;
    u16* kws   = qws + PLANE;
    u16* vws   = kws + PLANE;
    u16* ows   = vws + PLANE;
    u16* Opart = ows + PLANE;
    float* lpart = (float*)(Opart + (size_t)NSPLIT * PLANE);

    dim3 blk(256);
    proj_qkv<<<dim3(64, 4, 3), blk, 0, stream>>>(query, key, value, Wq, Wk, Wv,
                                                 bq, bk, bv, qws, kws, vws);
    flash<<<dim3(32 * NSPLIT, H, NB), blk, 0, stream>>>(qws, kws, vws, mask, Opart, lpart);
    reduce_split<<<dim3(2048), blk, 0, stream>>>(Opart, lpart, ows);
    proj_out<<<dim3(64, 4, 1), blk, 0, stream>>>(ows, Wo, bo, out);
}

// Round 8
// 247.818 us; speedup vs baseline: 1.6080x; 1.6080x over previous
//
#include <hip/hip_runtime.h>
#include <hip/hip_bf16.h>

#define H 8
#define DM 512
#define DK 64
#define LSEQ 4096
#define NB 2
#define NSPLIT 2
#define KSPAN (LSEQ / NSPLIT)   // keys per split = 2048
#define NIT (KSPAN / 64)        // 32 k-tiles per block

// 0.125 (1/sqrt(DK)) * log2(e): folded into Q so softmax uses exp2 directly
#define QSCALE 0.18033688011112042f

typedef float f32x4 __attribute__((ext_vector_type(4)));
typedef __bf16 bf16x8 __attribute__((ext_vector_type(8)));
typedef __bf16 bf16x2 __attribute__((ext_vector_type(2)));
typedef unsigned short u16;

__device__ __forceinline__ u16 f2bf(float f) {
    union { float f; unsigned u; } v{f};
    return (u16)((v.u + 0x8000u) >> 16);
}

__device__ __forceinline__ unsigned pkbf(float a, float b) {
#if __has_builtin(__builtin_amdgcn_cvt_pk_bf16_f32)
    union { bf16x2 v; unsigned u; } x;
    x.v = __builtin_amdgcn_cvt_pk_bf16_f32(a, b);
    return x.u;
#else
    union { float f; unsigned u; } x{a}, y{b};
    return ((x.u + 0x8000u) >> 16) | ((y.u + 0x8000u) & 0xffff0000u);
#endif
}

__device__ __forceinline__ ushort4 cvt4(float4 a) {
    union { ushort4 s; uint2 u; } o;
    o.u.x = pkbf(a.x, a.y);
    o.u.y = pkbf(a.z, a.w);
    return o.s;
}

__device__ __forceinline__ float2 ubf2(unsigned u) {
    union { float f; unsigned v; } a, b;
    a.v = u << 16;
    b.v = u & 0xffff0000u;
    return make_float2(a.f, b.f);
}

__device__ __forceinline__ float fexp2(float x) {
#if __has_builtin(__builtin_amdgcn_exp2f)
    return __builtin_amdgcn_exp2f(x);
#else
    return exp2f(x);
#endif
}

__device__ __forceinline__ f32x4 mfma32(bf16x8 a, bf16x8 b, f32x4 c) {
    return __builtin_amdgcn_mfma_f32_16x16x32_bf16(a, b, c, 0, 0, 0);
}

// ---------------------------------------------------------------------------
// QKV projection, 128x128 tile, REGISTER-DOUBLE-BUFFERED staging (flash's
// proven pattern: prefetch next k-tile into regs during compute, store after
// MFMAs, one barrier per iter). Budget check: ~200 VGPR peak < 256 @ (256,2).
// mode 0 (Q): scaled by QSCALE, (b,h,s,d); 1 (K): (b,h,s,d); 2 (V): (b,h,d,s)
// via LDS transpose.
// ---------------------------------------------------------------------------
__launch_bounds__(256, 2)
__global__ void proj_qkv(const float* __restrict__ Xq, const float* __restrict__ Xk,
                         const float* __restrict__ Xv,
                         const float* __restrict__ Wq, const float* __restrict__ Wk,
                         const float* __restrict__ Wv,
                         const float* __restrict__ bq, const float* __restrict__ bk,
                         const float* __restrict__ bv,
                         u16* __restrict__ qo, u16* __restrict__ ko, u16* __restrict__ vo)
{
    const int mode = blockIdx.z;
    const float* X    = (mode == 0) ? Xq : (mode == 1) ? Xk : Xv;
    const float* W    = (mode == 0) ? Wq : (mode == 1) ? Wk : Wv;
    const float* bias = (mode == 0) ? bq : (mode == 1) ? bk : bv;
    u16* out          = (mode == 0) ? qo : (mode == 1) ? ko : vo;

    __shared__ __align__(16) u16 As[2][128][72];
    __shared__ __align__(16) u16 Bs[2][128][72];

    const int tid  = threadIdx.x;
    const int wave = tid >> 6;
    const int lane = tid & 63;
    const int g    = lane >> 4;
    const int ln   = lane & 15;
    const int wr   = wave >> 1;
    const int wc   = wave & 1;

    const int m0 = blockIdx.x * 128;
    const int n0 = blockIdx.y * 128;

    float4 xa[8], wb[8];
    // prologue: tile 0
    #pragma unroll
    for (int i = 0; i < 8; ++i) {
        int idx = tid + 256 * i;
        int row = idx >> 4;
        int col = (idx & 15) * 4;
        xa[i] = *(const float4*)(X + (size_t)(m0 + row) * DM + col);
        wb[i] = *(const float4*)(W + (size_t)(n0 + row) * DM + col);
    }
    #pragma unroll
    for (int i = 0; i < 8; ++i) {
        int idx = tid + 256 * i;
        int row = idx >> 4;
        int col = (idx & 15) * 4;
        *(ushort4*)&As[0][row][col] = cvt4(xa[i]);
        *(ushort4*)&Bs[0][row][col] = cvt4(wb[i]);
    }

    f32x4 acc[4][4] = {};

    for (int kt = 0; kt < 8; ++kt) {
        const int cur = kt & 1;
        __syncthreads();

        if (kt < 7) {
            int kb = (kt + 1) * 64;
            #pragma unroll
            for (int i = 0; i < 8; ++i) {
                int idx = tid + 256 * i;
                int row = idx >> 4;
                int col = (idx & 15) * 4;
                xa[i] = *(const float4*)(X + (size_t)(m0 + row) * DM + kb + col);
                wb[i] = *(const float4*)(W + (size_t)(n0 + row) * DM + kb + col);
            }
        }

        bf16x8 af[4][2], bf[4][2];
        #pragma unroll
        for (int t = 0; t < 4; ++t) {
            af[t][0] = *(const bf16x8*)&As[cur][wr * 64 + t * 16 + ln][g * 8];
            af[t][1] = *(const bf16x8*)&As[cur][wr * 64 + t * 16 + ln][32 + g * 8];
            bf[t][0] = *(const bf16x8*)&Bs[cur][wc * 64 + t * 16 + ln][g * 8];
            bf[t][1] = *(const bf16x8*)&Bs[cur][wc * 64 + t * 16 + ln][32 + g * 8];
        }
        #pragma unroll
        for (int mt = 0; mt < 4; ++mt)
            #pragma unroll
            for (int nt = 0; nt < 4; ++nt) {
                acc[mt][nt] = mfma32(af[mt][0], bf[nt][0], acc[mt][nt]);
                acc[mt][nt] = mfma32(af[mt][1], bf[nt][1], acc[mt][nt]);
            }

        if (kt < 7) {
            int nxt = 1 - cur;
            #pragma unroll
            for (int i = 0; i < 8; ++i) {
                int idx = tid + 256 * i;
                int row = idx >> 4;
                int col = (idx & 15) * 4;
                *(ushort4*)&As[nxt][row][col] = cvt4(xa[i]);
                *(ushort4*)&Bs[nxt][row][col] = cvt4(wb[i]);
            }
        }
    }

    if (mode != 2) {
        #pragma unroll
        for (int nt = 0; nt < 4; ++nt) {
            int n  = n0 + wc * 64 + nt * 16 + ln;
            float bias_n = bias[n];
            int hh = n >> 6;
            int d  = n & (DK - 1);
            #pragma unroll
            for (int mt = 0; mt < 4; ++mt)
                #pragma unroll
                for (int r = 0; r < 4; ++r) {
                    int m  = m0 + wr * 64 + mt * 16 + g * 4 + r;
                    int bb = m >> 12;
                    int s  = m & (LSEQ - 1);
                    float val = acc[mt][nt][r] + bias_n;
                    if (mode == 0) val *= QSCALE;
                    out[(size_t)((bb * H + hh) * LSEQ + s) * DK + d] = f2bf(val);
                }
        }
    } else {
        __syncthreads();   // all waves done reading As before reuse as Ts
        u16* Ts = &As[0][0][0];
        #pragma unroll
        for (int nt = 0; nt < 4; ++nt) {
            int dl = wc * 64 + nt * 16 + ln;
            float bias_n = bias[n0 + dl];
            #pragma unroll
            for (int mt = 0; mt < 4; ++mt)
                #pragma unroll
                for (int r = 0; r < 4; ++r) {
                    int sl = wr * 64 + mt * 16 + g * 4 + r;
                    Ts[dl * 136 + sl] = f2bf(acc[mt][nt][r] + bias_n);
                }
        }
        __syncthreads();
        int dl   = tid >> 1;
        int half = tid & 1;
        int n  = n0 + dl;
        int hh = n >> 6;
        int d  = n & (DK - 1);
        int bb = m0 >> 12;
        int s0 = (m0 & (LSEQ - 1)) + half * 64;
        u16* dst = out + ((size_t)((bb * H + hh) * DK + d) * LSEQ + s0);
        const u16* srcp = Ts + dl * 136 + half * 64;
        #pragma unroll
        for (int i = 0; i < 8; ++i)
            *(uint4*)(dst + i * 8) = *(const uint4*)(srcp + i * 8);
    }
}

// ---------------------------------------------------------------------------
// Flash attention — EXACT round-6 version (103.6 µs measured). RULE (r5/r7):
// no control flow between the QK^T MFMAs and the P-pack — any branch there
// spills at the 128-VGPR/wave budget (WRITE_SIZE 17 -> 537 MB twice).
// ---------------------------------------------------------------------------
__launch_bounds__(256, 4)
__global__ void flash(const u16* __restrict__ qws, const u16* __restrict__ kws,
                      const u16* __restrict__ vws, const int* __restrict__ mask,
                      u16* __restrict__ Opart, float* __restrict__ lpart)
{
    __shared__ u16 Ks[2][64][72];
    __shared__ u16 Vs[2][64][72];   // [d][pi(key)]

    const int tid   = threadIdx.x;
    const int wave  = tid >> 6;
    const int lane  = tid & 63;
    const int g     = lane >> 4;
    const int ln    = lane & 15;
    const int b     = blockIdx.z;
    const int h     = blockIdx.y;
    const int qblk  = blockIdx.x & 31;
    const int split = blockIdx.x >> 5;
    const int q0    = qblk * 128;
    const int kstart = split * KSPAN;

    const u16* qp = qws + ((size_t)((b * H + h) * LSEQ) + q0 + wave * 32 + ln) * DK;
    const u16* kp = kws + (size_t)(b * H + h) * LSEQ * DK;
    const u16* vp = vws + (size_t)(b * H + h) * DK * LSEQ;
    const int* mp = mask + b * LSEQ;

    bf16x8 qf[2][2];
    qf[0][0] = *(const bf16x8*)(qp + g * 8);
    qf[0][1] = *(const bf16x8*)(qp + 32 + g * 8);
    qf[1][0] = *(const bf16x8*)(qp + 16 * DK + g * 8);
    qf[1][1] = *(const bf16x8*)(qp + 16 * DK + 32 + g * 8);

    union OU { unsigned u[4]; bf16x8 v; } onesu;
    onesu.u[0] = onesu.u[1] = onesu.u[2] = onesu.u[3] = 0x3F803F80u;
    const bf16x8 vones = onesu.v;

    f32x4 accO[2][4] = {};
    f32x4 accL[2] = {};

    const int row = tid >> 3;
    const int c   = tid & 7;
    const int vcol0 = ((2 * c) & 3) * 16 + (c >> 1) * 4;

    uint4 kr0, kr1, vr0, vr1;
    kr0 = *(const uint4*)(kp + (size_t)(kstart + row) * DK + c * 8);
    kr1 = *(const uint4*)(kp + (size_t)(kstart + row + 32) * DK + c * 8);
    vr0 = *(const uint4*)(vp + (size_t)row * LSEQ + kstart + c * 8);
    vr1 = *(const uint4*)(vp + (size_t)(row + 32) * LSEQ + kstart + c * 8);
    *(uint4*)&Ks[0][row][c * 8]      = kr0;
    *(uint4*)&Ks[0][row + 32][c * 8] = kr1;
    *(uint2*)&Vs[0][row][vcol0]           = make_uint2(vr0.x, vr0.y);
    *(uint2*)&Vs[0][row][vcol0 + 16]      = make_uint2(vr0.z, vr0.w);
    *(uint2*)&Vs[0][row + 32][vcol0]      = make_uint2(vr1.x, vr1.y);
    *(uint2*)&Vs[0][row + 32][vcol0 + 16] = make_uint2(vr1.z, vr1.w);

    for (int it = 0; it < NIT; ++it) {
        const int cur = it & 1;
        const int k0  = kstart + it * 64;
        __syncthreads();

        if (it < NIT - 1) {
            int kn = k0 + 64;
            kr0 = *(const uint4*)(kp + (size_t)(kn + row) * DK + c * 8);
            kr1 = *(const uint4*)(kp + (size_t)(kn + row + 32) * DK + c * 8);
            vr0 = *(const uint4*)(vp + (size_t)row * LSEQ + kn + c * 8);
            vr1 = *(const uint4*)(vp + (size_t)(row + 32) * LSEQ + kn + c * 8);
        }

        // S^T = K . Q^T for both q-subtiles (K-frags read once)
        f32x4 sc[2][4];
        #pragma unroll
        for (int kb = 0; kb < 4; ++kb) {
            bf16x8 kf0 = *(const bf16x8*)&Ks[cur][kb * 16 + ln][g * 8];
            bf16x8 kf1 = *(const bf16x8*)&Ks[cur][kb * 16 + ln][32 + g * 8];
            #pragma unroll
            for (int j = 0; j < 2; ++j) {
                f32x4 z = {};
                z = mfma32(kf0, qf[j][0], z);
                z = mfma32(kf1, qf[j][1], z);
                sc[j][kb] = z;
            }
        }

        // mask + exp2 (single unconditional path: one int4 live at a time)
        #pragma unroll
        for (int kb = 0; kb < 4; ++kb) {
            int4 mv = *(const int4*)(mp + k0 + kb * 16 + g * 4);
            #pragma unroll
            for (int j = 0; j < 2; ++j) {
                sc[j][kb][0] = fexp2(mv.x ? sc[j][kb][0] : -1e9f);
                sc[j][kb][1] = fexp2(mv.y ? sc[j][kb][1] : -1e9f);
                sc[j][kb][2] = fexp2(mv.z ? sc[j][kb][2] : -1e9f);
                sc[j][kb][3] = fexp2(mv.w ? sc[j][kb][3] : -1e9f);
            }
        }

        // pack P fragments (score regs are A-layout under formal-k remap)
        union PU { unsigned u[4]; bf16x8 v; } p01[2], p23[2];
        #pragma unroll
        for (int j = 0; j < 2; ++j) {
            p01[j].u[0] = pkbf(sc[j][0][0], sc[j][0][1]);
            p01[j].u[1] = pkbf(sc[j][0][2], sc[j][0][3]);
            p01[j].u[2] = pkbf(sc[j][1][0], sc[j][1][1]);
            p01[j].u[3] = pkbf(sc[j][1][2], sc[j][1][3]);
            p23[j].u[0] = pkbf(sc[j][2][0], sc[j][2][1]);
            p23[j].u[1] = pkbf(sc[j][2][2], sc[j][2][3]);
            p23[j].u[2] = pkbf(sc[j][3][0], sc[j][3][1]);
            p23[j].u[3] = pkbf(sc[j][3][2], sc[j][3][3]);
        }

        // l row-sums via ones-MFMA; O += P . V
        #pragma unroll
        for (int j = 0; j < 2; ++j) {
            accL[j] = mfma32(p01[j].v, vones, accL[j]);
            accL[j] = mfma32(p23[j].v, vones, accL[j]);
        }
        #pragma unroll
        for (int t = 0; t < 4; ++t) {
            bf16x8 vb01 = *(const bf16x8*)&Vs[cur][t * 16 + ln][g * 16];
            bf16x8 vb23 = *(const bf16x8*)&Vs[cur][t * 16 + ln][g * 16 + 8];
            #pragma unroll
            for (int j = 0; j < 2; ++j) {
                accO[j][t] = mfma32(p01[j].v, vb01, accO[j][t]);
                accO[j][t] = mfma32(p23[j].v, vb23, accO[j][t]);
            }
        }

        if (it < NIT - 1) {
            int nxt = 1 - cur;
            *(uint4*)&Ks[nxt][row][c * 8]      = kr0;
            *(uint4*)&Ks[nxt][row + 32][c * 8] = kr1;
            *(uint2*)&Vs[nxt][row][vcol0]           = make_uint2(vr0.x, vr0.y);
            *(uint2*)&Vs[nxt][row][vcol0 + 16]      = make_uint2(vr0.z, vr0.w);
            *(uint2*)&Vs[nxt][row + 32][vcol0]      = make_uint2(vr1.x, vr1.y);
            *(uint2*)&Vs[nxt][row + 32][vcol0 + 16] = make_uint2(vr1.z, vr1.w);
        }
    }

    // accL[j][r] = l for q-row (g*4+r), replicated over ln.
    const size_t PLANE = (size_t)NB * LSEQ * DM;
    u16* opp = Opart + (size_t)split * PLANE;

    #pragma unroll
    for (int j = 0; j < 2; ++j) {
        if (ln == 0) {
            #pragma unroll
            for (int r = 0; r < 4; ++r)
                lpart[(size_t)split * (NB * H * LSEQ) + ((size_t)(b * H + h) * LSEQ)
                      + q0 + wave * 32 + j * 16 + g * 4 + r] = accL[j][r];
        }
        #pragma unroll
        for (int r = 0; r < 4; ++r) {
            float linv = 1.0f / accL[j][r];
            size_t base = ((size_t)(b * LSEQ) + q0 + wave * 32 + j * 16 + g * 4 + r) * DM + h * DK;
            #pragma unroll
            for (int t = 0; t < 4; ++t)
                opp[base + t * 16 + ln] = f2bf(accO[j][t][r] * linv);
        }
    }
}

// ---------------------------------------------------------------------------
// Split-K combine: ows = (l0*Ohat0 + l1*Ohat1) / (l0+l1), bf16 out.
// ---------------------------------------------------------------------------
__launch_bounds__(256, 4)
__global__ void reduce_split(const u16* __restrict__ Opart, const float* __restrict__ lpart,
                             u16* __restrict__ ows)
{
    const size_t PLANE = (size_t)NB * LSEQ * DM;
    size_t gid  = (size_t)blockIdx.x * 256 + threadIdx.x;
    size_t flat = gid * 8;

    int b   = (int)(flat >> 21);            // LSEQ*DM = 2^21
    int rem = (int)(flat & ((1 << 21) - 1));
    int q   = rem >> 9;                      // DM = 512
    int hh  = (rem & 511) >> 6;
    size_t lidx = ((size_t)(b * H + hh) * LSEQ) + q;

    float l0 = lpart[lidx];
    float l1 = lpart[(size_t)NB * H * LSEQ + lidx];
    float inv = 1.0f / (l0 + l1);
    float w0 = l0 * inv, w1 = l1 * inv;

    uint4 c0 = *(const uint4*)(Opart + flat);
    uint4 c1 = *(const uint4*)(Opart + PLANE + flat);

    float o[8];
    {
        float2 a, bv;
        a = ubf2(c0.x); bv = ubf2(c1.x); o[0] = w0 * a.x + w1 * bv.x; o[1] = w0 * a.y + w1 * bv.y;
        a = ubf2(c0.y); bv = ubf2(c1.y); o[2] = w0 * a.x + w1 * bv.x; o[3] = w0 * a.y + w1 * bv.y;
        a = ubf2(c0.z); bv = ubf2(c1.z); o[4] = w0 * a.x + w1 * bv.x; o[5] = w0 * a.y + w1 * bv.y;
        a = ubf2(c0.w); bv = ubf2(c1.w); o[6] = w0 * a.x + w1 * bv.x; o[7] = w0 * a.y + w1 * bv.y;
    }
    uint4 r;
    r.x = pkbf(o[0], o[1]);
    r.y = pkbf(o[2], o[3]);
    r.z = pkbf(o[4], o[5]);
    r.w = pkbf(o[6], o[7]);
    *(uint4*)(ows + flat) = r;
}

// ---------------------------------------------------------------------------
// Output projection, 128x64 tile (grid 512 = 2 blocks/CU; the 128x128 r7
// variant was 256 blocks = 1/CU, latency-starved), register-double-buffered.
// ---------------------------------------------------------------------------
__launch_bounds__(256, 2)
__global__ void proj_out(const u16* __restrict__ A, const float* __restrict__ Wo,
                         const float* __restrict__ bo, float* __restrict__ out)
{
    __shared__ __align__(16) u16 As[2][128][72];
    __shared__ __align__(16) u16 Bs[2][64][72];

    const int tid  = threadIdx.x;
    const int wave = tid >> 6;
    const int lane = tid & 63;
    const int g    = lane >> 4;
    const int ln   = lane & 15;

    const int m0 = blockIdx.x * 128;
    const int n0 = blockIdx.y * 64;

    uint4 aa[4];
    float4 wb[4];
    #pragma unroll
    for (int i = 0; i < 4; ++i) {
        int idx = tid + 256 * i;
        int row = idx >> 3;
        int col = (idx & 7) * 8;
        aa[i] = *(const uint4*)(A + (size_t)(m0 + row) * DM + col);
        int idb = tid + 256 * i;
        int rwb = idb >> 4;
        int cwb = (idb & 15) * 4;
        wb[i] = *(const float4*)(Wo + (size_t)(n0 + rwb) * DM + cwb);
    }
    #pragma unroll
    for (int i = 0; i < 4; ++i) {
        int idx = tid + 256 * i;
        int row = idx >> 3;
        int col = (idx & 7) * 8;
        *(uint4*)&As[0][row][col] = aa[i];
        int idb = tid + 256 * i;
        int rwb = idb >> 4;
        int cwb = (idb & 15) * 4;
        *(ushort4*)&Bs[0][rwb][cwb] = cvt4(wb[i]);
    }

    f32x4 acc[2][4] = {};

    for (int kt = 0; kt < 8; ++kt) {
        const int cur = kt & 1;
        __syncthreads();

        if (kt < 7) {
            int kb = (kt + 1) * 64;
            #pragma unroll
            for (int i = 0; i < 4; ++i) {
                int idx = tid + 256 * i;
                int row = idx >> 3;
                int col = (idx & 7) * 8;
                aa[i] = *(const uint4*)(A + (size_t)(m0 + row) * DM + kb + col);
                int idb = tid + 256 * i;
                int rwb = idb >> 4;
                int cwb = (idb & 15) * 4;
                wb[i] = *(const float4*)(Wo + (size_t)(n0 + rwb) * DM + kb + cwb);
            }
        }

        bf16x8 af[2][2], bf[4][2];
        #pragma unroll
        for (int mt = 0; mt < 2; ++mt) {
            af[mt][0] = *(const bf16x8*)&As[cur][wave * 32 + mt * 16 + ln][g * 8];
            af[mt][1] = *(const bf16x8*)&As[cur][wave * 32 + mt * 16 + ln][32 + g * 8];
        }
        #pragma unroll
        for (int nt = 0; nt < 4; ++nt) {
            bf[nt][0] = *(const bf16x8*)&Bs[cur][nt * 16 + ln][g * 8];
            bf[nt][1] = *(const bf16x8*)&Bs[cur][nt * 16 + ln][32 + g * 8];
        }
        #pragma unroll
        for (int mt = 0; mt < 2; ++mt)
            #pragma unroll
            for (int nt = 0; nt < 4; ++nt) {
                acc[mt][nt] = mfma32(af[mt][0], bf[nt][0], acc[mt][nt]);
                acc[mt][nt] = mfma32(af[mt][1], bf[nt][1], acc[mt][nt]);
            }

        if (kt < 7) {
            int nxt = 1 - cur;
            #pragma unroll
            for (int i = 0; i < 4; ++i) {
                int idx = tid + 256 * i;
                int row = idx >> 3;
                int col = (idx & 7) * 8;
                *(uint4*)&As[nxt][row][col] = aa[i];
                int idb = tid + 256 * i;
                int rwb = idb >> 4;
                int cwb = (idb & 15) * 4;
                *(ushort4*)&Bs[nxt][rwb][cwb] = cvt4(wb[i]);
            }
        }
    }

    #pragma unroll
    for (int nt = 0; nt < 4; ++nt) {
        int n = n0 + nt * 16 + ln;
        float bias_n = bo[n];
        #pragma unroll
        for (int mt = 0; mt < 2; ++mt)
            #pragma unroll
            for (int r = 0; r < 4; ++r) {
                int m = m0 + wave * 32 + mt * 16 + g * 4 + r;
                out[(size_t)m * DM + n] = acc[mt][nt][r] + bias_n;
            }
    }
}

// ---------------------------------------------------------------------------
extern "C" void kernel_launch(void* const* d_in, const int* in_sizes, int n_in,
                              void* d_out, int out_size, void* d_ws, size_t ws_size,
                              hipStream_t stream) {
    (void)in_sizes; (void)n_in; (void)out_size; (void)ws_size;

    const float* query = (const float*)d_in[0];
    const float* key   = (const float*)d_in[1];
    const float* value = (const float*)d_in[2];
    const int*   mask  = (const int*)d_in[3];
    const float* Wq = (const float*)d_in[4];
    const float* bq = (const float*)d_in[5];
    const float* Wk = (const float*)d_in[6];
    const float* bk = (const float*)d_in[7];
    const float* Wv = (const float*)d_in[8];
    const float* bv = (const float*)d_in[9];
    const float* Wo = (const float*)d_in[10];
    const float* bo = (const float*)d_in[11];
    float* out = (float*)d_out;

    // ws layout (u16 elems): qws | kws | vws | ows | Opart(2 planes) | lpart(f32)
    const size_t PLANE = (size_t)NB * H * LSEQ * DK;   // 4,194,304
    u16* qws   = (u16*)d_ws;
    u16* kws   = qws + PLANE;
    u16* vws   = kws + PLANE;
    u16* ows   = vws + PLANE;
    u16* Opart = ows + PLANE;
    float* lpart = (float*)(Opart + (size_t)NSPLIT * PLANE);

    dim3 blk(256);
    proj_qkv<<<dim3(64, 4, 3), blk, 0, stream>>>(query, key, value, Wq, Wk, Wv,
                                                 bq, bk, bv, qws, kws, vws);
    flash<<<dim3(32 * NSPLIT, H, NB), blk, 0, stream>>>(qws, kws, vws, mask, Opart, lpart);
    reduce_split<<<dim3(2048), blk, 0, stream>>>(Opart, lpart, ows);
    proj_out<<<dim3(64, 8, 1), blk, 0, stream>>>(ows, Wo, bo, out);
}

// Round 9
// 233.082 us; speedup vs baseline: 1.7097x; 1.0632x over previous
//
#include <hip/hip_runtime.h>
#include <hip/hip_bf16.h>

#define H 8
#define DM 512
#define DK 64
#define LSEQ 4096
#define NB 2
#define NSPLIT 2
#define KSPAN (LSEQ / NSPLIT)   // keys per split = 2048
#define NIT (KSPAN / 64)        // 32 k-tiles per block

// 0.125 (1/sqrt(DK)) * log2(e): folded into Q so softmax uses exp2 directly
#define QSCALE 0.18033688011112042f

typedef float f32x4 __attribute__((ext_vector_type(4)));
typedef __bf16 bf16x8 __attribute__((ext_vector_type(8)));
typedef __bf16 bf16x2 __attribute__((ext_vector_type(2)));
typedef unsigned short u16;

__device__ __forceinline__ u16 f2bf(float f) {
    union { float f; unsigned u; } v{f};
    return (u16)((v.u + 0x8000u) >> 16);
}

__device__ __forceinline__ unsigned pkbf(float a, float b) {
#if __has_builtin(__builtin_amdgcn_cvt_pk_bf16_f32)
    union { bf16x2 v; unsigned u; } x;
    x.v = __builtin_amdgcn_cvt_pk_bf16_f32(a, b);
    return x.u;
#else
    union { float f; unsigned u; } x{a}, y{b};
    return ((x.u + 0x8000u) >> 16) | ((y.u + 0x8000u) & 0xffff0000u);
#endif
}

__device__ __forceinline__ ushort4 cvt4(float4 a) {
    union { ushort4 s; uint2 u; } o;
    o.u.x = pkbf(a.x, a.y);
    o.u.y = pkbf(a.z, a.w);
    return o.s;
}

__device__ __forceinline__ float2 ubf2(unsigned u) {
    union { float f; unsigned v; } a, b;
    a.v = u << 16;
    b.v = u & 0xffff0000u;
    return make_float2(a.f, b.f);
}

__device__ __forceinline__ float fexp2(float x) {
#if __has_builtin(__builtin_amdgcn_exp2f)
    return __builtin_amdgcn_exp2f(x);
#else
    return exp2f(x);
#endif
}

__device__ __forceinline__ f32x4 mfma32(bf16x8 a, bf16x8 b, f32x4 c) {
    return __builtin_amdgcn_mfma_f32_16x16x32_bf16(a, b, c, 0, 0, 0);
}

// ---------------------------------------------------------------------------
// QKV projection, 128x128 tile, register-double-buffered (r8 structure).
// NEW (r9): masked keys are ZEROED at projection time for K (mode 1) and V
// (mode 2) — this moves the attention mask entirely out of flash's hot loop:
//   masked key -> k=0 -> s=0 -> p=exp2(0)=1; PV contribution 1*0=0; the
//   exact overcount of l (= n_masked, bf16-exact 1.0 each) is subtracted in
//   flash's epilogue from a prologue ballot-count.
// ---------------------------------------------------------------------------
__launch_bounds__(256, 2)
__global__ void proj_qkv(const float* __restrict__ Xq, const float* __restrict__ Xk,
                         const float* __restrict__ Xv,
                         const float* __restrict__ Wq, const float* __restrict__ Wk,
                         const float* __restrict__ Wv,
                         const float* __restrict__ bq, const float* __restrict__ bk,
                         const float* __restrict__ bv,
                         const int* __restrict__ mask,
                         u16* __restrict__ qo, u16* __restrict__ ko, u16* __restrict__ vo)
{
    const int mode = blockIdx.z;
    const float* X    = (mode == 0) ? Xq : (mode == 1) ? Xk : Xv;
    const float* W    = (mode == 0) ? Wq : (mode == 1) ? Wk : Wv;
    const float* bias = (mode == 0) ? bq : (mode == 1) ? bk : bv;
    u16* out          = (mode == 0) ? qo : (mode == 1) ? ko : vo;

    __shared__ __align__(16) u16 As[2][128][72];
    __shared__ __align__(16) u16 Bs[2][128][72];

    const int tid  = threadIdx.x;
    const int wave = tid >> 6;
    const int lane = tid & 63;
    const int g    = lane >> 4;
    const int ln   = lane & 15;
    const int wr   = wave >> 1;
    const int wc   = wave & 1;

    const int m0 = blockIdx.x * 128;
    const int n0 = blockIdx.y * 128;

    float4 xa[8], wb[8];
    #pragma unroll
    for (int i = 0; i < 8; ++i) {
        int idx = tid + 256 * i;
        int row = idx >> 4;
        int col = (idx & 15) * 4;
        xa[i] = *(const float4*)(X + (size_t)(m0 + row) * DM + col);
        wb[i] = *(const float4*)(W + (size_t)(n0 + row) * DM + col);
    }
    #pragma unroll
    for (int i = 0; i < 8; ++i) {
        int idx = tid + 256 * i;
        int row = idx >> 4;
        int col = (idx & 15) * 4;
        *(ushort4*)&As[0][row][col] = cvt4(xa[i]);
        *(ushort4*)&Bs[0][row][col] = cvt4(wb[i]);
    }

    f32x4 acc[4][4] = {};

    for (int kt = 0; kt < 8; ++kt) {
        const int cur = kt & 1;
        __syncthreads();

        if (kt < 7) {
            int kb = (kt + 1) * 64;
            #pragma unroll
            for (int i = 0; i < 8; ++i) {
                int idx = tid + 256 * i;
                int row = idx >> 4;
                int col = (idx & 15) * 4;
                xa[i] = *(const float4*)(X + (size_t)(m0 + row) * DM + kb + col);
                wb[i] = *(const float4*)(W + (size_t)(n0 + row) * DM + kb + col);
            }
        }

        bf16x8 af[4][2], bf[4][2];
        #pragma unroll
        for (int t = 0; t < 4; ++t) {
            af[t][0] = *(const bf16x8*)&As[cur][wr * 64 + t * 16 + ln][g * 8];
            af[t][1] = *(const bf16x8*)&As[cur][wr * 64 + t * 16 + ln][32 + g * 8];
            bf[t][0] = *(const bf16x8*)&Bs[cur][wc * 64 + t * 16 + ln][g * 8];
            bf[t][1] = *(const bf16x8*)&Bs[cur][wc * 64 + t * 16 + ln][32 + g * 8];
        }
        #pragma unroll
        for (int mt = 0; mt < 4; ++mt)
            #pragma unroll
            for (int nt = 0; nt < 4; ++nt) {
                acc[mt][nt] = mfma32(af[mt][0], bf[nt][0], acc[mt][nt]);
                acc[mt][nt] = mfma32(af[mt][1], bf[nt][1], acc[mt][nt]);
            }

        if (kt < 7) {
            int nxt = 1 - cur;
            #pragma unroll
            for (int i = 0; i < 8; ++i) {
                int idx = tid + 256 * i;
                int row = idx >> 4;
                int col = (idx & 15) * 4;
                *(ushort4*)&As[nxt][row][col] = cvt4(xa[i]);
                *(ushort4*)&Bs[nxt][row][col] = cvt4(wb[i]);
            }
        }
    }

    if (mode != 2) {
        #pragma unroll
        for (int nt = 0; nt < 4; ++nt) {
            int n  = n0 + wc * 64 + nt * 16 + ln;
            float bias_n = bias[n];
            int hh = n >> 6;
            int d  = n & (DK - 1);
            #pragma unroll
            for (int mt = 0; mt < 4; ++mt)
                #pragma unroll
                for (int r = 0; r < 4; ++r) {
                    int m  = m0 + wr * 64 + mt * 16 + g * 4 + r;
                    int bb = m >> 12;
                    int s  = m & (LSEQ - 1);
                    float val = acc[mt][nt][r] + bias_n;
                    if (mode == 0) val *= QSCALE;
                    else           val = mask[bb * LSEQ + s] ? val : 0.0f;  // zero masked K rows
                    out[(size_t)((bb * H + hh) * LSEQ + s) * DK + d] = f2bf(val);
                }
        }
    } else {
        __syncthreads();   // all waves done reading As before reuse as Ts
        u16* Ts = &As[0][0][0];
        const int bb = m0 >> 12;
        const int s0 = m0 & (LSEQ - 1);
        #pragma unroll
        for (int nt = 0; nt < 4; ++nt) {
            int dl = wc * 64 + nt * 16 + ln;
            float bias_n = bias[n0 + dl];
            #pragma unroll
            for (int mt = 0; mt < 4; ++mt)
                #pragma unroll
                for (int r = 0; r < 4; ++r) {
                    int sl = wr * 64 + mt * 16 + g * 4 + r;
                    float val = acc[mt][nt][r] + bias_n;
                    val = mask[bb * LSEQ + s0 + sl] ? val : 0.0f;           // zero masked V rows
                    Ts[dl * 136 + sl] = f2bf(val);
                }
        }
        __syncthreads();
        int dl   = tid >> 1;
        int half = tid & 1;
        int n  = n0 + dl;
        int hh = n >> 6;
        int d  = n & (DK - 1);
        int sb = s0 + half * 64;
        u16* dst = out + ((size_t)((bb * H + hh) * DK + d) * LSEQ + sb);
        const u16* srcp = Ts + dl * 136 + half * 64;
        #pragma unroll
        for (int i = 0; i < 8; ++i)
            *(uint4*)(dst + i * 8) = *(const uint4*)(srcp + i * 8);
    }
}

// ---------------------------------------------------------------------------
// Flash attention, transposed-S, q=32/wave, 2-way split-K.
// r9: NO mask logic in the hot loop (masked K/V rows pre-zeroed by proj_qkv;
// the exact l overcount n_masked is counted in the prologue via ballot and
// subtracted in the epilogue). Hot loop stays straight-line — RULE (r5/r7):
// no control flow between the QK^T MFMAs and the P-pack at the 128-VGPR
// budget, or it spills (WRITE_SIZE 17 -> 537 MB, twice).
// ---------------------------------------------------------------------------
__launch_bounds__(256, 4)
__global__ void flash(const u16* __restrict__ qws, const u16* __restrict__ kws,
                      const u16* __restrict__ vws, const int* __restrict__ mask,
                      u16* __restrict__ Opart, float* __restrict__ lpart)
{
    __shared__ u16 Ks[2][64][72];
    __shared__ u16 Vs[2][64][72];   // [d][pi(key)]

    const int tid   = threadIdx.x;
    const int wave  = tid >> 6;
    const int lane  = tid & 63;
    const int g     = lane >> 4;
    const int ln    = lane & 15;
    const int b     = blockIdx.z;
    const int h     = blockIdx.y;
    const int qblk  = blockIdx.x & 31;
    const int split = blockIdx.x >> 5;
    const int q0    = qblk * 128;
    const int kstart = split * KSPAN;

    const u16* qp = qws + ((size_t)((b * H + h) * LSEQ) + q0 + wave * 32 + ln) * DK;
    const u16* kp = kws + (size_t)(b * H + h) * LSEQ * DK;
    const u16* vp = vws + (size_t)(b * H + h) * DK * LSEQ;
    const int* mp = mask + b * LSEQ;

    // count masked keys in this split (wave-uniform; hot loop is mask-free)
    int nmask = 0;
    for (int t = 0; t < NIT; ++t) {
        int mval = mp[kstart + t * 64 + lane];
        unsigned long long bal = __ballot(mval == 0);
        nmask += (int)__popcll(bal);
    }
    const float fnmask = (float)nmask;

    bf16x8 qf[2][2];
    qf[0][0] = *(const bf16x8*)(qp + g * 8);
    qf[0][1] = *(const bf16x8*)(qp + 32 + g * 8);
    qf[1][0] = *(const bf16x8*)(qp + 16 * DK + g * 8);
    qf[1][1] = *(const bf16x8*)(qp + 16 * DK + 32 + g * 8);

    union OU { unsigned u[4]; bf16x8 v; } onesu;
    onesu.u[0] = onesu.u[1] = onesu.u[2] = onesu.u[3] = 0x3F803F80u;
    const bf16x8 vones = onesu.v;

    f32x4 accO[2][4] = {};
    f32x4 accL[2] = {};

    const int row = tid >> 3;
    const int c   = tid & 7;
    const int vcol0 = ((2 * c) & 3) * 16 + (c >> 1) * 4;

    uint4 kr0, kr1, vr0, vr1;
    kr0 = *(const uint4*)(kp + (size_t)(kstart + row) * DK + c * 8);
    kr1 = *(const uint4*)(kp + (size_t)(kstart + row + 32) * DK + c * 8);
    vr0 = *(const uint4*)(vp + (size_t)row * LSEQ + kstart + c * 8);
    vr1 = *(const uint4*)(vp + (size_t)(row + 32) * LSEQ + kstart + c * 8);
    *(uint4*)&Ks[0][row][c * 8]      = kr0;
    *(uint4*)&Ks[0][row + 32][c * 8] = kr1;
    *(uint2*)&Vs[0][row][vcol0]           = make_uint2(vr0.x, vr0.y);
    *(uint2*)&Vs[0][row][vcol0 + 16]      = make_uint2(vr0.z, vr0.w);
    *(uint2*)&Vs[0][row + 32][vcol0]      = make_uint2(vr1.x, vr1.y);
    *(uint2*)&Vs[0][row + 32][vcol0 + 16] = make_uint2(vr1.z, vr1.w);

    for (int it = 0; it < NIT; ++it) {
        const int cur = it & 1;
        __syncthreads();

        if (it < NIT - 1) {
            int kn = kstart + it * 64 + 64;
            kr0 = *(const uint4*)(kp + (size_t)(kn + row) * DK + c * 8);
            kr1 = *(const uint4*)(kp + (size_t)(kn + row + 32) * DK + c * 8);
            vr0 = *(const uint4*)(vp + (size_t)row * LSEQ + kn + c * 8);
            vr1 = *(const uint4*)(vp + (size_t)(row + 32) * LSEQ + kn + c * 8);
        }

        // S^T = K . Q^T for both q-subtiles (K-frags read once)
        f32x4 sc[2][4];
        #pragma unroll
        for (int kb = 0; kb < 4; ++kb) {
            bf16x8 kf0 = *(const bf16x8*)&Ks[cur][kb * 16 + ln][g * 8];
            bf16x8 kf1 = *(const bf16x8*)&Ks[cur][kb * 16 + ln][32 + g * 8];
            #pragma unroll
            for (int j = 0; j < 2; ++j) {
                f32x4 z = {};
                z = mfma32(kf0, qf[j][0], z);
                z = mfma32(kf1, qf[j][1], z);
                sc[j][kb] = z;
            }
        }

        // exp2 directly — mask already baked into K (s=0 -> p=1, V=0)
        #pragma unroll
        for (int kb = 0; kb < 4; ++kb)
            #pragma unroll
            for (int j = 0; j < 2; ++j) {
                sc[j][kb][0] = fexp2(sc[j][kb][0]);
                sc[j][kb][1] = fexp2(sc[j][kb][1]);
                sc[j][kb][2] = fexp2(sc[j][kb][2]);
                sc[j][kb][3] = fexp2(sc[j][kb][3]);
            }

        // pack P fragments (score regs are A-layout under formal-k remap)
        union PU { unsigned u[4]; bf16x8 v; } p01[2], p23[2];
        #pragma unroll
        for (int j = 0; j < 2; ++j) {
            p01[j].u[0] = pkbf(sc[j][0][0], sc[j][0][1]);
            p01[j].u[1] = pkbf(sc[j][0][2], sc[j][0][3]);
            p01[j].u[2] = pkbf(sc[j][1][0], sc[j][1][1]);
            p01[j].u[3] = pkbf(sc[j][1][2], sc[j][1][3]);
            p23[j].u[0] = pkbf(sc[j][2][0], sc[j][2][1]);
            p23[j].u[1] = pkbf(sc[j][2][2], sc[j][2][3]);
            p23[j].u[2] = pkbf(sc[j][3][0], sc[j][3][1]);
            p23[j].u[3] = pkbf(sc[j][3][2], sc[j][3][3]);
        }

        // l row-sums via ones-MFMA; O += P . V
        #pragma unroll
        for (int j = 0; j < 2; ++j) {
            accL[j] = mfma32(p01[j].v, vones, accL[j]);
            accL[j] = mfma32(p23[j].v, vones, accL[j]);
        }
        #pragma unroll
        for (int t = 0; t < 4; ++t) {
            bf16x8 vb01 = *(const bf16x8*)&Vs[cur][t * 16 + ln][g * 16];
            bf16x8 vb23 = *(const bf16x8*)&Vs[cur][t * 16 + ln][g * 16 + 8];
            #pragma unroll
            for (int j = 0; j < 2; ++j) {
                accO[j][t] = mfma32(p01[j].v, vb01, accO[j][t]);
                accO[j][t] = mfma32(p23[j].v, vb23, accO[j][t]);
            }
        }

        if (it < NIT - 1) {
            int nxt = 1 - cur;
            *(uint4*)&Ks[nxt][row][c * 8]      = kr0;
            *(uint4*)&Ks[nxt][row + 32][c * 8] = kr1;
            *(uint2*)&Vs[nxt][row][vcol0]           = make_uint2(vr0.x, vr0.y);
            *(uint2*)&Vs[nxt][row][vcol0 + 16]      = make_uint2(vr0.z, vr0.w);
            *(uint2*)&Vs[nxt][row + 32][vcol0]      = make_uint2(vr1.x, vr1.y);
            *(uint2*)&Vs[nxt][row + 32][vcol0 + 16] = make_uint2(vr1.z, vr1.w);
        }
    }

    // accL[j][r] = l + n_masked for q-row (g*4+r); subtract the exact overcount.
    const size_t PLANE = (size_t)NB * LSEQ * DM;
    u16* opp = Opart + (size_t)split * PLANE;

    #pragma unroll
    for (int j = 0; j < 2; ++j) {
        if (ln == 0) {
            #pragma unroll
            for (int r = 0; r < 4; ++r)
                lpart[(size_t)split * (NB * H * LSEQ) + ((size_t)(b * H + h) * LSEQ)
                      + q0 + wave * 32 + j * 16 + g * 4 + r] = accL[j][r] - fnmask;
        }
        #pragma unroll
        for (int r = 0; r < 4; ++r) {
            float linv = 1.0f / (accL[j][r] - fnmask);
            size_t base = ((size_t)(b * LSEQ) + q0 + wave * 32 + j * 16 + g * 4 + r) * DM + h * DK;
            #pragma unroll
            for (int t = 0; t < 4; ++t)
                opp[base + t * 16 + ln] = f2bf(accO[j][t][r] * linv);
        }
    }
}

// ---------------------------------------------------------------------------
// Split-K combine: ows = (l0*Ohat0 + l1*Ohat1) / (l0+l1), bf16 out.
// ---------------------------------------------------------------------------
__launch_bounds__(256, 4)
__global__ void reduce_split(const u16* __restrict__ Opart, const float* __restrict__ lpart,
                             u16* __restrict__ ows)
{
    const size_t PLANE = (size_t)NB * LSEQ * DM;
    size_t gid  = (size_t)blockIdx.x * 256 + threadIdx.x;
    size_t flat = gid * 8;

    int b   = (int)(flat >> 21);            // LSEQ*DM = 2^21
    int rem = (int)(flat & ((1 << 21) - 1));
    int q   = rem >> 9;                      // DM = 512
    int hh  = (rem & 511) >> 6;
    size_t lidx = ((size_t)(b * H + hh) * LSEQ) + q;

    float l0 = lpart[lidx];
    float l1 = lpart[(size_t)NB * H * LSEQ + lidx];
    float inv = 1.0f / (l0 + l1);
    float w0 = l0 * inv, w1 = l1 * inv;

    uint4 c0 = *(const uint4*)(Opart + flat);
    uint4 c1 = *(const uint4*)(Opart + PLANE + flat);

    float o[8];
    {
        float2 a, bv;
        a = ubf2(c0.x); bv = ubf2(c1.x); o[0] = w0 * a.x + w1 * bv.x; o[1] = w0 * a.y + w1 * bv.y;
        a = ubf2(c0.y); bv = ubf2(c1.y); o[2] = w0 * a.x + w1 * bv.x; o[3] = w0 * a.y + w1 * bv.y;
        a = ubf2(c0.z); bv = ubf2(c1.z); o[4] = w0 * a.x + w1 * bv.x; o[5] = w0 * a.y + w1 * bv.y;
        a = ubf2(c0.w); bv = ubf2(c1.w); o[6] = w0 * a.x + w1 * bv.x; o[7] = w0 * a.y + w1 * bv.y;
    }
    uint4 r;
    r.x = pkbf(o[0], o[1]);
    r.y = pkbf(o[2], o[3]);
    r.z = pkbf(o[4], o[5]);
    r.w = pkbf(o[6], o[7]);
    *(uint4*)(ows + flat) = r;
}

// ---------------------------------------------------------------------------
// Output projection, 128x64 tile, register-double-buffered (r8, unchanged).
// ---------------------------------------------------------------------------
__launch_bounds__(256, 2)
__global__ void proj_out(const u16* __restrict__ A, const float* __restrict__ Wo,
                         const float* __restrict__ bo, float* __restrict__ out)
{
    __shared__ __align__(16) u16 As[2][128][72];
    __shared__ __align__(16) u16 Bs[2][64][72];

    const int tid  = threadIdx.x;
    const int wave = tid >> 6;
    const int lane = tid & 63;
    const int g    = lane >> 4;
    const int ln   = lane & 15;

    const int m0 = blockIdx.x * 128;
    const int n0 = blockIdx.y * 64;

    uint4 aa[4];
    float4 wb[4];
    #pragma unroll
    for (int i = 0; i < 4; ++i) {
        int idx = tid + 256 * i;
        int row = idx >> 3;
        int col = (idx & 7) * 8;
        aa[i] = *(const uint4*)(A + (size_t)(m0 + row) * DM + col);
        int rwb = idx >> 4;
        int cwb = (idx & 15) * 4;
        wb[i] = *(const float4*)(Wo + (size_t)(n0 + rwb) * DM + cwb);
    }
    #pragma unroll
    for (int i = 0; i < 4; ++i) {
        int idx = tid + 256 * i;
        int row = idx >> 3;
        int col = (idx & 7) * 8;
        *(uint4*)&As[0][row][col] = aa[i];
        int rwb = idx >> 4;
        int cwb = (idx & 15) * 4;
        *(ushort4*)&Bs[0][rwb][cwb] = cvt4(wb[i]);
    }

    f32x4 acc[2][4] = {};

    for (int kt = 0; kt < 8; ++kt) {
        const int cur = kt & 1;
        __syncthreads();

        if (kt < 7) {
            int kb = (kt + 1) * 64;
            #pragma unroll
            for (int i = 0; i < 4; ++i) {
                int idx = tid + 256 * i;
                int row = idx >> 3;
                int col = (idx & 7) * 8;
                aa[i] = *(const uint4*)(A + (size_t)(m0 + row) * DM + kb + col);
                int rwb = idx >> 4;
                int cwb = (idx & 15) * 4;
                wb[i] = *(const float4*)(Wo + (size_t)(n0 + rwb) * DM + kb + cwb);
            }
        }

        bf16x8 af[2][2], bf[4][2];
        #pragma unroll
        for (int mt = 0; mt < 2; ++mt) {
            af[mt][0] = *(const bf16x8*)&As[cur][wave * 32 + mt * 16 + ln][g * 8];
            af[mt][1] = *(const bf16x8*)&As[cur][wave * 32 + mt * 16 + ln][32 + g * 8];
        }
        #pragma unroll
        for (int nt = 0; nt < 4; ++nt) {
            bf[nt][0] = *(const bf16x8*)&Bs[cur][nt * 16 + ln][g * 8];
            bf[nt][1] = *(const bf16x8*)&Bs[cur][nt * 16 + ln][32 + g * 8];
        }
        #pragma unroll
        for (int mt = 0; mt < 2; ++mt)
            #pragma unroll
            for (int nt = 0; nt < 4; ++nt) {
                acc[mt][nt] = mfma32(af[mt][0], bf[nt][0], acc[mt][nt]);
                acc[mt][nt] = mfma32(af[mt][1], bf[nt][1], acc[mt][nt]);
            }

        if (kt < 7) {
            int nxt = 1 - cur;
            #pragma unroll
            for (int i = 0; i < 4; ++i) {
                int idx = tid + 256 * i;
                int row = idx >> 3;
                int col = (idx & 7) * 8;
                *(uint4*)&As[nxt][row][col] = aa[i];
                int rwb = idx >> 4;
                int cwb = (idx & 15) * 4;
                *(ushort4*)&Bs[nxt][rwb][cwb] = cvt4(wb[i]);
            }
        }
    }

    #pragma unroll
    for (int nt = 0; nt < 4; ++nt) {
        int n = n0 + nt * 16 + ln;
        float bias_n = bo[n];
        #pragma unroll
        for (int mt = 0; mt < 2; ++mt)
            #pragma unroll
            for (int r = 0; r < 4; ++r) {
                int m = m0 + wave * 32 + mt * 16 + g * 4 + r;
                out[(size_t)m * DM + n] = acc[mt][nt][r] + bias_n;
            }
    }
}

// ---------------------------------------------------------------------------
extern "C" void kernel_launch(void* const* d_in, const int* in_sizes, int n_in,
                              void* d_out, int out_size, void* d_ws, size_t ws_size,
                              hipStream_t stream) {
    (void)in_sizes; (void)n_in; (void)out_size; (void)ws_size;

    const float* query = (const float*)d_in[0];
    const float* key   = (const float*)d_in[1];
    const float* value = (const float*)d_in[2];
    const int*   mask  = (const int*)d_in[3];
    const float* Wq = (const float*)d_in[4];
    const float* bq = (const float*)d_in[5];
    const float* Wk = (const float*)d_in[6];
    const float* bk = (const float*)d_in[7];
    const float* Wv = (const float*)d_in[8];
    const float* bv = (const float*)d_in[9];
    const float* Wo = (const float*)d_in[10];
    const float* bo = (const float*)d_in[11];
    float* out = (float*)d_out;

    // ws layout (u16 elems): qws | kws | vws | ows | Opart(2 planes) | lpart(f32)
    const size_t PLANE = (size_t)NB * H * LSEQ * DK;   // 4,194,304
    u16* qws   = (u16*)d_ws;
    u16* kws   = qws + PLANE;
    u16* vws   = kws + PLANE;
    u16* ows   = vws + PLANE;
    u16* Opart = ows + PLANE;
    float* lpart = (float*)(Opart + (size_t)NSPLIT * PLANE);

    dim3 blk(256);
    proj_qkv<<<dim3(64, 4, 3), blk, 0, stream>>>(query, key, value, Wq, Wk, Wv,
                                                 bq, bk, bv, mask, qws, kws, vws);
    flash<<<dim3(32 * NSPLIT, H, NB), blk, 0, stream>>>(qws, kws, vws, mask, Opart, lpart);
    reduce_split<<<dim3(2048), blk, 0, stream>>>(Opart, lpart, ows);
    proj_out<<<dim3(64, 8, 1), blk, 0, stream>>>(ows, Wo, bo, out);
}